// Round 1
// baseline (116.191 us; speedup 1.0000x reference)
//
#include <hip/hip_runtime.h>
#include <hip/hip_bf16.h>
#include <hip/hip_fp16.h>

// GeneratorSDF: latent-conditioned MLP SDF on a 128^3 grid (fp32 I/O).
// dims: 67 -> 128 -> 64 -> 32 -> 1 (relu, relu, relu, sigmoid)
//
// R23 = R22 minus ALL main-loop LDS. Theory: 53.5us sits 2.6x above the
// 20.7us MFMA floor with MfmaUtil 31.7 / VALUBusy 42.5 / 4.55M LDS
// bank-conflict cycles -> latency-bound on the A3(ds_write)->bphase
// (ds_read) h2 round-trip + LDS pipe contention, not throughput-bound.
// The layer2 C-layout (ch = mt*16 + quad*4 + reg, col = point = l15) maps
// onto the layer3 B-layout (ch = 32*kb + 8*quad + j, col = l15) by a pure
// quad-space permutation: with packed pairs u(mt,s) = pk(c[2s],c[2s+1]),
//   permlane32_swap(u(2kb,s), u(2kb+1,s)); permlane16_swap(A, B)
// yields exactly frag words t=s (in A) and t=2+s (in B) for all 4 quads.
// 8 swap instrs/pg replace 4x ds_write_b64 + 2x ds_read_b128 + the whole
// double-buffer/prefetch machinery. The final 32-dot cross-quad reduce
// likewise becomes swap16+add, swap32+add (kills zf/cphase LDS), with a
// quad0-masked 64B coalesced store. Main loop: no LDS, no barriers.
// Keeps from R18/R22: fp16 datapath, a2[16]+a3[4] register-resident,
// pinned twp/tbp, jrow-outer 4x8, 4-way-parallel W1 fold, (256,2),
// grid 1024 (2048 pts/block).
// MFMA layouts (verified m89/m91): A[m=lane&15][k=quad*8+j],
// B[k=quad*8+j][n=lane&15], C/D row=quad*4+reg, col=lane&15.

#define NPTS (128 * 128 * 128)

typedef float f32x4_t __attribute__((ext_vector_type(4)));
typedef float f32x2_t __attribute__((ext_vector_type(2)));
typedef __fp16 g16x2_t __attribute__((ext_vector_type(2)));    // VALU half2 (cvt_pkrtz type)
typedef _Float16 h16x8_t __attribute__((ext_vector_type(8)));  // MFMA fragment
typedef unsigned u32x2_t __attribute__((ext_vector_type(2)));

__device__ __forceinline__ unsigned h2u(g16x2_t h) {
    unsigned u;
    __builtin_memcpy(&u, &h, 4);
    return u;
}
__device__ __forceinline__ g16x2_t u2h(unsigned u) {
    g16x2_t h;
    __builtin_memcpy(&h, &u, 4);
    return h;
}

// permlane32_swap: a'[lane>=32] = b[lane-32]; b'[lane<32] = a[lane+32]
__device__ __forceinline__ void pl32_swap(unsigned& a, unsigned& b) {
#if __has_builtin(__builtin_amdgcn_permlane32_swap)
    u32x2_t r = __builtin_amdgcn_permlane32_swap(a, b, false, false);
    a = r[0];
    b = r[1];
#else
    asm("v_permlane32_swap_b32 %0, %1" : "+v"(a), "+v"(b));
#endif
}
// permlane16_swap: a'[lane&16] = b[lane-16]; b'[!(lane&16)] = a[lane+16]
__device__ __forceinline__ void pl16_swap(unsigned& a, unsigned& b) {
#if __has_builtin(__builtin_amdgcn_permlane16_swap)
    u32x2_t r = __builtin_amdgcn_permlane16_swap(a, b, false, false);
    a = r[0];
    b = r[1];
#else
    asm("v_permlane16_swap_b32 %0, %1" : "+v"(a), "+v"(b));
#endif
}

__global__ __launch_bounds__(256, 2) void mlp_kernel(
    const float* __restrict__ x,  const float* __restrict__ W1,
    const float* __restrict__ b1, const float* __restrict__ W2,
    const float* __restrict__ b2, const float* __restrict__ W3,
    const float* __restrict__ b3, const float* __restrict__ W4,
    const float* __restrict__ b4, float* __restrict__ out) {
    __shared__ __align__(16) unsigned s_basep[16][64];  // half2 {base[2c],base[2c+1]} per j
    __shared__ __align__(16) unsigned s_wcp[64];        // half2 wc pairs
    __shared__ __align__(16) float s_b2[64];
    __shared__ __align__(16) float s_b3[32];
    __shared__ __align__(16) float s_w4[32];
    // Staging only (22.5 KB): w2a[16][64][8] halves (0..8191) + w3a[4][64][8]
    // (8192..10239) + W1-fold partials (floats at shorts 10240..11263,
    // transient). No runtime LDS use -- main loop is LDS-free.
    __shared__ __align__(16) unsigned short s_u[11264];

    const int t = threadIdx.x;
    const int w = t >> 6;
    const int lane = t & 63;
    const int quad = lane >> 4;
    const int l15 = lane & 15;
    const float step = 2.0f / 127.0f;

    // ================= per-block prep, phase 1 (all 256 threads) =============
    // W1 fold partials: thread covers channel-pair p = t&63, c in [h*16,(h+1)*16)
    {
        const int p = t & 63, h = t >> 6;
        const float* r0 = W1 + (2 * p) * 67 + h * 16;
        const float* r1 = r0 + 67;
        const float* xh = x + h * 16;
        float s0 = 0.0f, s1 = 0.0f;
#pragma unroll
        for (int c = 0; c < 16; ++c) {
            const float xc = xh[c];
            s0 = fmaf(r0[c], xc, s0);
            s1 = fmaf(r1[c], xc, s1);
        }
        float2* psum = (float2*)&s_u[10240];   // [h][p], 4 x 64 float2
        psum[h * 64 + p] = make_float2(s0, s1);
    }
    // W2 [64][128] -> f16 A-frag staging (pairs along k)
    const float2* W2v = (const float2*)W2;
#pragma unroll
    for (int it = 0; it < 16; ++it) {
        int pidx = t + 256 * it;
        int idx2 = pidx * 2;
        int o = idx2 >> 7, k = idx2 & 127;
        int mt = o >> 4, lm = o & 15;
        int kb = k >> 5, q = (k >> 3) & 3, jj = k & 7;
        float2 v = W2v[pidx];
        *(unsigned*)&s_u[(mt * 4 + kb) * 512 + (q * 16 + lm) * 8 + jj] =
            h2u(__builtin_amdgcn_cvt_pkrtz(v.x, v.y));
    }
    // W3 [32][64] -> f16 A-frag staging
    const float2* W3v = (const float2*)W3;
#pragma unroll
    for (int it = 0; it < 4; ++it) {
        int pidx = t + 256 * it;
        int idx2 = pidx * 2;
        int o = idx2 >> 6, k = idx2 & 63;
        int mt = o >> 4, lm = o & 15;
        int kb = k >> 5, q = (k >> 3) & 3, jj = k & 7;
        float2 v = W3v[pidx];
        *(unsigned*)&s_u[8192 + (mt * 2 + kb) * 512 + (q * 16 + lm) * 8 + jj] =
            h2u(__builtin_amdgcn_cvt_pkrtz(v.x, v.y));
    }
    if (t < 64) s_b2[t] = b2[t];
    if (t < 32) {
        s_b3[t] = b3[t];
        s_w4[t] = W4[t];
    }
    const float bias4 = b4[0];
    __syncthreads();

    // ================= prep phase 2 (t<64): combine partials + pack tables ====
    if (t < 64) {
        const float2* psum = (const float2*)&s_u[10240];
        float2 q0 = psum[t], q1 = psum[64 + t], q2 = psum[128 + t], q3 = psum[192 + t];
        float s0 = b1[2 * t] + (q0.x + q1.x) + (q2.x + q3.x);
        float s1 = b1[2 * t + 1] + (q0.y + q1.y) + (q2.y + q3.y);
        const float* r0 = W1 + (2 * t) * 67;
        const float* r1 = r0 + 67;
        const float pa = -1.0f + step * (float)(blockIdx.x >> 3);   // gi
        const float base0 = fmaf(r0[64], pa, s0);
        const float base1 = fmaf(r1[64], pa, s1);
        const float wb0 = r0[65], wb1 = r1[65];
        const int gj0 = (blockIdx.x & 7) * 16;
        s_wcp[t] = h2u(__builtin_amdgcn_cvt_pkrtz(r0[66], r1[66]));
#pragma unroll
        for (int j = 0; j < 16; ++j) {
            const float pb = -1.0f + step * (float)(gj0 + j);
            s_basep[j][t] = h2u(__builtin_amdgcn_cvt_pkrtz(
                fmaf(wb0, pb, base0), fmaf(wb1, pb, base1)));
        }
    }
    __syncthreads();

    // ================= per-wave fragment preload =================
    h16x8_t a2[16];
#pragma unroll
    for (int f = 0; f < 16; ++f) a2[f] = *(const h16x8_t*)&s_u[f * 512 + lane * 8];
    h16x8_t a3[4];
#pragma unroll
    for (int f = 0; f < 4; ++f) a3[f] = *(const h16x8_t*)&s_u[8192 + f * 512 + lane * 8];
    f32x4_t b2q[4];
#pragma unroll
    for (int mt = 0; mt < 4; ++mt) b2q[mt] = *(const f32x4_t*)&s_b2[mt * 16 + quad * 4];
    f32x4_t b3q[2];
    f32x2_t w4lo[2], w4hi[2];
#pragma unroll
    for (int mt = 0; mt < 2; ++mt) {
        b3q[mt] = *(const f32x4_t*)&s_b3[mt * 16 + quad * 4];
        float4 wq = *(const float4*)&s_w4[mt * 16 + quad * 4];
        w4lo[mt][0] = wq.x; w4lo[mt][1] = wq.y;
        w4hi[mt][0] = wq.z; w4hi[mt][1] = wq.w;
    }
    // wc pairs: loop-invariant, 16 packed regs, pinned
    unsigned twp[16];
#pragma unroll
    for (int kb = 0; kb < 4; ++kb) {
        uint4 v = *(const uint4*)&s_wcp[kb * 16 + quad * 4];
        twp[kb * 4 + 0] = v.x; twp[kb * 4 + 1] = v.y;
        twp[kb * 4 + 2] = v.z; twp[kb * 4 + 3] = v.w;
    }
#pragma unroll
    for (int i = 0; i < 16; ++i) asm volatile("" : "+v"(twp[i]));
    // No third barrier: staging LDS is never overwritten (no union handoff).

    const f32x2_t zero2 = {0.0f, 0.0f};
    const g16x2_t zero2h = {(__fp16)0.0f, (__fp16)0.0f};
    const int outbase = blockIdx.x * 2048 + w * 512;

    // ========== jrow-outer main loop (LDS-free, barrier-free) ==========
    for (int jrow = 0; jrow < 4; ++jrow) {
        // base pairs for this jrow: 16 packed regs, pinned
        const unsigned* bp = &s_basep[w * 4 + jrow][0];
        unsigned tbp[16];
#pragma unroll
        for (int kb = 0; kb < 4; ++kb) {
            uint4 v = *(const uint4*)&bp[kb * 16 + quad * 4];
            tbp[kb * 4 + 0] = v.x; tbp[kb * 4 + 1] = v.y;
            tbp[kb * 4 + 2] = v.z; tbp[kb * 4 + 3] = v.w;
        }
#pragma unroll
        for (int i = 0; i < 16; ++i) asm volatile("" : "+v"(tbp[i]));

#pragma unroll 2
        for (int pg = 0; pg < 8; ++pg) {
            const int ng = jrow * 8 + pg;
            const float pc = fmaf(step, (float)((pg * 16) + l15), -1.0f);
            const g16x2_t pc2 = __builtin_amdgcn_cvt_pkrtz(pc, pc);

            // ---- A1: h1 via packed f16 fma/max, straight into B-fragments ----
            h16x8_t bfrag[4];
#pragma unroll
            for (int kb = 0; kb < 4; ++kb) {
                union { h16x8_t v; g16x2_t h[4]; } bb;
#pragma unroll
                for (int p = 0; p < 4; ++p) {
                    g16x2_t hh = __builtin_elementwise_fma(
                        u2h(twp[kb * 4 + p]), pc2, u2h(tbp[kb * 4 + p]));
                    bb.h[p] = __builtin_elementwise_max(hh, zero2h);
                }
                bfrag[kb] = bb.v;
            }
            // ---- A2: layer 2 MFMA (f16), bias in C-init ----
            f32x4_t acc2[4];
#pragma unroll
            for (int mt = 0; mt < 4; ++mt) {
                f32x4_t c = b2q[mt];
#pragma unroll
                for (int kb = 0; kb < 4; ++kb)
                    c = __builtin_amdgcn_mfma_f32_16x16x32_f16(a2[mt * 4 + kb], bfrag[kb], c, 0, 0, 0);
                acc2[mt] = c;
            }
            // ---- pack + relu: u[mt][s] = ch {16mt + 4q + 2s, +1} ----
            unsigned u[4][2];
#pragma unroll
            for (int mt = 0; mt < 4; ++mt) {
                u[mt][0] = h2u(__builtin_elementwise_max(
                    __builtin_amdgcn_cvt_pkrtz(acc2[mt][0], acc2[mt][1]), zero2h));
                u[mt][1] = h2u(__builtin_elementwise_max(
                    __builtin_amdgcn_cvt_pkrtz(acc2[mt][2], acc2[mt][3]), zero2h));
            }
            // ---- quad-space permute: h2 C-layout -> layer3 B-fragments ----
            // per (kb,s): swap32 then swap16 on (u[2kb][s], u[2kb+1][s])
            // -> A holds frag word t=s, B holds frag word t=2+s (all quads).
            h16x8_t b3f[2];
#pragma unroll
            for (int kb = 0; kb < 2; ++kb) {
                union { h16x8_t v; unsigned wd[4]; } fb;
#pragma unroll
                for (int s = 0; s < 2; ++s) {
                    unsigned A = u[2 * kb][s], B = u[2 * kb + 1][s];
                    pl32_swap(A, B);
                    pl16_swap(A, B);
                    fb.wd[s] = A;        // t = s   (k-words j = 2s, 2s+1)
                    fb.wd[2 + s] = B;    // t = 2+s
                }
                b3f[kb] = fb.v;
            }
            // ---- layer 3 MFMA + relu + w4 dot (in registers) ----
            f32x2_t z2 = zero2;
#pragma unroll
            for (int mt = 0; mt < 2; ++mt) {
                f32x4_t c = b3q[mt];
                c = __builtin_amdgcn_mfma_f32_16x16x32_f16(a3[mt * 2 + 0], b3f[0], c, 0, 0, 0);
                c = __builtin_amdgcn_mfma_f32_16x16x32_f16(a3[mt * 2 + 1], b3f[1], c, 0, 0, 0);
                f32x2_t h01 = __builtin_elementwise_max((f32x2_t){c[0], c[1]}, zero2);
                f32x2_t h23 = __builtin_elementwise_max((f32x2_t){c[2], c[3]}, zero2);
                z2 = __builtin_elementwise_fma(w4lo[mt], h01, z2);
                z2 = __builtin_elementwise_fma(w4hi[mt], h23, z2);
            }
            // ---- cross-quad reduce via swaps (no LDS) ----
            float z = z2[0] + z2[1];
            unsigned za = __builtin_bit_cast(unsigned, z), zb = za;
            pl16_swap(za, zb);  // za=[z0,z0,z2,z2], zb=[z1,z1,z3,z3]
            z = __builtin_bit_cast(float, za) + __builtin_bit_cast(float, zb);
            za = __builtin_bit_cast(unsigned, z); zb = za;
            pl32_swap(za, zb);  // za=lo-half bcast, zb=hi-half bcast
            z = __builtin_bit_cast(float, za) + __builtin_bit_cast(float, zb) + bias4;
            // ---- sigmoid + quad0-masked coalesced 64B store ----
            const float r = 1.0f / (1.0f + __expf(-z));
            if (quad == 0) out[outbase + ng * 16 + l15] = r;
        }
    }
}

extern "C" void kernel_launch(void* const* d_in, const int* in_sizes, int n_in,
                              void* d_out, int out_size, void* d_ws, size_t ws_size,
                              hipStream_t stream) {
    mlp_kernel<<<NPTS / 2048, 256, 0, stream>>>(
        (const float*)d_in[0], (const float*)d_in[1], (const float*)d_in[2],
        (const float*)d_in[3], (const float*)d_in[4], (const float*)d_in[5],
        (const float*)d_in[6], (const float*)d_in[7], (const float*)d_in[8],
        (float*)d_out);
}